// Round 1
// baseline (116.265 us; speedup 1.0000x reference)
//
#include <hip/hip_runtime.h>

// out[b,k] = (WHT_2048(concat(x1[b],x2[b]))[k])^2 / 2048
// One wave (64 lanes) per row; 32 floats per lane.
// k = jo*256 + lane*4 + ji  (jo in [0,8), ji in [0,4))
//   k bits {0,1}   = ji   -> in-register stages (done per-chunk at load time)
//   k bits {2..7}  = lane -> cross-lane stages: DPP (xor1,2,4,8), swizzle (16), permlane32_swap (32)
//   k bits {8,9,10}= jo   -> in-register stages (done last)
// Stages on disjoint bits commute, so this order equals the reference WHT.

typedef float f32x4 __attribute__((ext_vector_type(4)));
typedef unsigned int u32x2 __attribute__((ext_vector_type(2)));

template <int CTRL>
__device__ __forceinline__ float dpp_xmov(float x) {
    return __int_as_float(__builtin_amdgcn_update_dpp(
        0, __float_as_int(x), CTRL, 0xF, 0xF, true));
}

// All 5 lane-xor stages for bits 2..6 of k (lane bits 0..4):
//   xor1: quad_perm [1,0,3,2]=0xB1 ; xor2: quad_perm [2,3,0,1]=0x4E
//   xor4 = xor3(0x1B) ∘ xor7(row_half_mirror 0x141)
//   xor8 = xor7(0x141) ∘ xor15(row_mirror 0x140)
//   xor16: ds_swizzle BitMode xor_mask=16 -> 0x401F
__device__ __forceinline__ float lane_chain(float x, float s1, float s2,
                                            float s4, float s8, float s16) {
    x = fmaf(s1, x, dpp_xmov<0xB1>(x));
    x = fmaf(s2, x, dpp_xmov<0x4E>(x));
    x = fmaf(s4, x, dpp_xmov<0x141>(dpp_xmov<0x1B>(x)));
    x = fmaf(s8, x, dpp_xmov<0x140>(dpp_xmov<0x141>(x)));
    x = fmaf(s16, x, __int_as_float(
            __builtin_amdgcn_ds_swizzle(__float_as_int(x), 0x401F)));
    return x;
}

// xor32 butterfly on two registers via v_permlane32_swap (VALU pipe, no LDS).
// swap(x,y): r0 = {x_lo, y_lo}, r1 = {x_hi, y_hi}   (per-lane: r0[l<32]=x[l],
// r0[l>=32]=y[l-32]; r1[l<32]=x[l+32]; r1[l>=32]=y[l]).
// a=r0+r1, b=r0-r1 hold both butterfly outputs, lane-misplaced; a second
// swap redistributes: out_x = {a_lo, b_lo}, out_y = {a_hi, b_hi}.
__device__ __forceinline__ void xor32_pair(float& x, float& y) {
    u32x2 r = __builtin_amdgcn_permlane32_swap(
        __float_as_uint(x), __float_as_uint(y), false, false);
    const float lo = __uint_as_float(r[0]);
    const float hi = __uint_as_float(r[1]);
    const float a = lo + hi;
    const float b = lo - hi;
    u32x2 r2 = __builtin_amdgcn_permlane32_swap(
        __float_as_uint(a), __float_as_uint(b), false, false);
    x = __uint_as_float(r2[0]);
    y = __uint_as_float(r2[1]);
}

__global__ __launch_bounds__(256) void qf_wht_kernel(const float* __restrict__ x1,
                                                     const float* __restrict__ x2,
                                                     float* __restrict__ out,
                                                     int nrows) {
    const int wave = threadIdx.x >> 6;
    const int lane = threadIdx.x & 63;
    const int row  = blockIdx.x * 4 + wave;
    if (row >= nrows) return;

    const float s1  = (lane & 1)  ? -1.0f : 1.0f;
    const float s2  = (lane & 2)  ? -1.0f : 1.0f;
    const float s4  = (lane & 4)  ? -1.0f : 1.0f;
    const float s8  = (lane & 8)  ? -1.0f : 1.0f;
    const float s16 = (lane & 16) ? -1.0f : 1.0f;

    // ---- issue all 8 loads up front (full MLP), nontemporal ----
    const float* __restrict__ p1 = x1 + (size_t)row * 1024 + lane * 4;
    const float* __restrict__ p2 = x2 + (size_t)row * 1024 + lane * 4;
    f32x4 f[8];
#pragma unroll
    for (int jo = 0; jo < 4; ++jo)
        f[jo] = __builtin_nontemporal_load(
            reinterpret_cast<const f32x4*>(p1 + jo * 256));
#pragma unroll
    for (int jo = 4; jo < 8; ++jo)
        f[jo] = __builtin_nontemporal_load(
            reinterpret_cast<const f32x4*>(p2 + (jo - 4) * 256));

    // ---- per-chunk: bits {0,1} in-register, then all 6 lane stages ----
    // Each chunk only needs its own load back (descending vmcnt), so the
    // lane-stage chains overlap the remaining loads' HBM latency.
    float v[32];
#pragma unroll
    for (int jo = 0; jo < 8; ++jo) {
        const float a01 = f[jo][0] + f[jo][1];
        const float d01 = f[jo][0] - f[jo][1];
        const float a23 = f[jo][2] + f[jo][3];
        const float d23 = f[jo][2] - f[jo][3];
        float c0 = a01 + a23;   // ji=0
        float c1 = d01 + d23;   // ji=1
        float c2 = a01 - a23;   // ji=2
        float c3 = d01 - d23;   // ji=3

        c0 = lane_chain(c0, s1, s2, s4, s8, s16);
        c1 = lane_chain(c1, s1, s2, s4, s8, s16);
        c2 = lane_chain(c2, s1, s2, s4, s8, s16);
        c3 = lane_chain(c3, s1, s2, s4, s8, s16);

        xor32_pair(c0, c1);
        xor32_pair(c2, c3);

        v[jo * 4 + 0] = c0;
        v[jo * 4 + 1] = c1;
        v[jo * 4 + 2] = c2;
        v[jo * 4 + 3] = c3;
    }

    // ---- k bits {8,9,10}: in-register butterflies across jo (j bits 2,3,4) ----
#pragma unroll
    for (int m = 4; m <= 16; m <<= 1) {
#pragma unroll
        for (int j = 0; j < 32; ++j) {
            if ((j & m) == 0) {
                const float a = v[j];
                const float b = v[j | m];
                v[j]     = a + b;
                v[j | m] = a - b;
            }
        }
    }

    // ---- square, scale, coalesced nontemporal float4 stores ----
    const float scale = 1.0f / 2048.0f;
    float* __restrict__ po = out + (size_t)row * 2048 + lane * 4;
#pragma unroll
    for (int jo = 0; jo < 8; ++jo) {
        f32x4 o;
        o[0] = v[jo * 4 + 0] * v[jo * 4 + 0] * scale;
        o[1] = v[jo * 4 + 1] * v[jo * 4 + 1] * scale;
        o[2] = v[jo * 4 + 2] * v[jo * 4 + 2] * scale;
        o[3] = v[jo * 4 + 3] * v[jo * 4 + 3] * scale;
        __builtin_nontemporal_store(o, reinterpret_cast<f32x4*>(po + jo * 256));
    }
}

extern "C" void kernel_launch(void* const* d_in, const int* in_sizes, int n_in,
                              void* d_out, int out_size, void* d_ws, size_t ws_size,
                              hipStream_t stream) {
    const float* x1 = (const float*)d_in[0];
    const float* x2 = (const float*)d_in[1];
    float* out = (float*)d_out;

    const int nrows = in_sizes[0] / 1024;           // 8192
    const int blocks = (nrows + 3) / 4;             // 4 rows per 256-thread block
    qf_wht_kernel<<<blocks, 256, 0, stream>>>(x1, x2, out, nrows);
}

// Round 2
// 110.587 us; speedup vs baseline: 1.0514x; 1.0514x over previous
//
#include <hip/hip_runtime.h>

// out[b,k] = (WHT_2048(concat(x1[b],x2[b]))[k])^2 / 2048
// One wave (64 lanes) per row; 32 floats per lane.
// k = jo*256 + lane*4 + ji  (jo in [0,8), ji in [0,4))
//   k bits {0,1}   = ji   -> in-register stages (done per-chunk at load time)
//   k bits {2..7}  = lane -> cross-lane stages: DPP (xor1,2,4,8), swizzle (16), permlane32_swap (32)
//   k bits {8,9,10}= jo   -> in-register stages (done last)
// Stages on disjoint bits commute, so this order equals the reference WHT.
//
// NOTE: loads/stores are PLAIN cached accesses. Inputs (64 MiB) stay resident
// in the 256 MiB Infinity Cache across iterations; nontemporal hints forced
// them to HBM and cost ~5 us (round-1 regression).

typedef float f32x4 __attribute__((ext_vector_type(4)));
typedef unsigned int u32x2 __attribute__((ext_vector_type(2)));

template <int CTRL>
__device__ __forceinline__ float dpp_xmov(float x) {
    return __int_as_float(__builtin_amdgcn_update_dpp(
        0, __float_as_int(x), CTRL, 0xF, 0xF, true));
}

// All 5 lane-xor stages for bits 2..6 of k (lane bits 0..4):
//   xor1: quad_perm [1,0,3,2]=0xB1 ; xor2: quad_perm [2,3,0,1]=0x4E
//   xor4 = xor3(0x1B) ∘ xor7(row_half_mirror 0x141)
//   xor8 = xor7(0x141) ∘ xor15(row_mirror 0x140)
//   xor16: ds_swizzle BitMode xor_mask=16 -> 0x401F
__device__ __forceinline__ float lane_chain(float x, float s1, float s2,
                                            float s4, float s8, float s16) {
    x = fmaf(s1, x, dpp_xmov<0xB1>(x));
    x = fmaf(s2, x, dpp_xmov<0x4E>(x));
    x = fmaf(s4, x, dpp_xmov<0x141>(dpp_xmov<0x1B>(x)));
    x = fmaf(s8, x, dpp_xmov<0x140>(dpp_xmov<0x141>(x)));
    x = fmaf(s16, x, __int_as_float(
            __builtin_amdgcn_ds_swizzle(__float_as_int(x), 0x401F)));
    return x;
}

// xor32 butterfly on two registers via v_permlane32_swap (VALU pipe, no LDS).
// swap(x,y): r0 = {x_lo, y_lo}, r1 = {x_hi, y_hi}.
// a=r0+r1, b=r0-r1 hold both butterfly outputs, lane-misplaced; a second
// swap redistributes: out_x = {a_lo, b_lo}, out_y = {a_hi, b_hi}.
__device__ __forceinline__ void xor32_pair(float& x, float& y) {
    u32x2 r = __builtin_amdgcn_permlane32_swap(
        __float_as_uint(x), __float_as_uint(y), false, false);
    const float lo = __uint_as_float(r[0]);
    const float hi = __uint_as_float(r[1]);
    const float a = lo + hi;
    const float b = lo - hi;
    u32x2 r2 = __builtin_amdgcn_permlane32_swap(
        __float_as_uint(a), __float_as_uint(b), false, false);
    x = __uint_as_float(r2[0]);
    y = __uint_as_float(r2[1]);
}

__global__ __launch_bounds__(256) void qf_wht_kernel(const float* __restrict__ x1,
                                                     const float* __restrict__ x2,
                                                     float* __restrict__ out,
                                                     int nrows) {
    const int wave = threadIdx.x >> 6;
    const int lane = threadIdx.x & 63;
    const int row  = blockIdx.x * 4 + wave;
    if (row >= nrows) return;

    const float s1  = (lane & 1)  ? -1.0f : 1.0f;
    const float s2  = (lane & 2)  ? -1.0f : 1.0f;
    const float s4  = (lane & 4)  ? -1.0f : 1.0f;
    const float s8  = (lane & 8)  ? -1.0f : 1.0f;
    const float s16 = (lane & 16) ? -1.0f : 1.0f;

    // ---- issue all 8 loads up front (full MLP), cached ----
    const float* __restrict__ p1 = x1 + (size_t)row * 1024 + lane * 4;
    const float* __restrict__ p2 = x2 + (size_t)row * 1024 + lane * 4;
    f32x4 f[8];
#pragma unroll
    for (int jo = 0; jo < 4; ++jo)
        f[jo] = *reinterpret_cast<const f32x4*>(p1 + jo * 256);
#pragma unroll
    for (int jo = 4; jo < 8; ++jo)
        f[jo] = *reinterpret_cast<const f32x4*>(p2 + (jo - 4) * 256);

    // ---- per-chunk: bits {0,1} in-register, then all 6 lane stages ----
    // Each chunk only needs its own load back (descending vmcnt), so the
    // lane-stage chains overlap the remaining loads' latency.
    float v[32];
#pragma unroll
    for (int jo = 0; jo < 8; ++jo) {
        const float a01 = f[jo][0] + f[jo][1];
        const float d01 = f[jo][0] - f[jo][1];
        const float a23 = f[jo][2] + f[jo][3];
        const float d23 = f[jo][2] - f[jo][3];
        float c0 = a01 + a23;   // ji=0
        float c1 = d01 + d23;   // ji=1
        float c2 = a01 - a23;   // ji=2
        float c3 = d01 - d23;   // ji=3

        c0 = lane_chain(c0, s1, s2, s4, s8, s16);
        c1 = lane_chain(c1, s1, s2, s4, s8, s16);
        c2 = lane_chain(c2, s1, s2, s4, s8, s16);
        c3 = lane_chain(c3, s1, s2, s4, s8, s16);

        xor32_pair(c0, c1);
        xor32_pair(c2, c3);

        v[jo * 4 + 0] = c0;
        v[jo * 4 + 1] = c1;
        v[jo * 4 + 2] = c2;
        v[jo * 4 + 3] = c3;
    }

    // ---- k bits {8,9,10}: in-register butterflies across jo (j bits 2,3,4) ----
#pragma unroll
    for (int m = 4; m <= 16; m <<= 1) {
#pragma unroll
        for (int j = 0; j < 32; ++j) {
            if ((j & m) == 0) {
                const float a = v[j];
                const float b = v[j | m];
                v[j]     = a + b;
                v[j | m] = a - b;
            }
        }
    }

    // ---- square, scale, coalesced float4 stores ----
    const float scale = 1.0f / 2048.0f;
    float* __restrict__ po = out + (size_t)row * 2048 + lane * 4;
#pragma unroll
    for (int jo = 0; jo < 8; ++jo) {
        f32x4 o;
        o[0] = v[jo * 4 + 0] * v[jo * 4 + 0] * scale;
        o[1] = v[jo * 4 + 1] * v[jo * 4 + 1] * scale;
        o[2] = v[jo * 4 + 2] * v[jo * 4 + 2] * scale;
        o[3] = v[jo * 4 + 3] * v[jo * 4 + 3] * scale;
        *reinterpret_cast<f32x4*>(po + jo * 256) = o;
    }
}

extern "C" void kernel_launch(void* const* d_in, const int* in_sizes, int n_in,
                              void* d_out, int out_size, void* d_ws, size_t ws_size,
                              hipStream_t stream) {
    const float* x1 = (const float*)d_in[0];
    const float* x2 = (const float*)d_in[1];
    float* out = (float*)d_out;

    const int nrows = in_sizes[0] / 1024;           // 8192
    const int blocks = (nrows + 3) / 4;             // 4 rows per 256-thread block
    qf_wht_kernel<<<blocks, 256, 0, stream>>>(x1, x2, out, nrows);
}